// Round 5
// baseline (1547.895 us; speedup 1.0000x reference)
//
#include <hip/hip_runtime.h>
#include <math.h>

#define TT 10
#define BB 32
#define CIN 3
#define COUT 64
#define HH 64
#define WW 64
#define HW (HH*WW)           // 4096
#define DECAY 0.2f
#define INH 1.625f
#define CPG 16               // channels per group (one wave owns 16 channels)

// ---------------------------------------------------------------------------
// Pass 1: thr[t][c] = max over (B,H,W) of conv output.
// Block = (t, b, 4-row group); 256 thr = 64 pixels x 4 channel-groups.
// c-outer/k-inner (round-3-proven shape: scalar acc, full unroll, regs only);
// per-channel max accumulated in registers over 4 rows, one shuffle-reduce,
// then atomicMax (sortable-uint).
// ---------------------------------------------------------------------------
__global__ __launch_bounds__(256) void thr_kernel(
    const float* __restrict__ x,        // (T,B,3,64,64)
    const float* __restrict__ Wt,       // (64,3,3,3)
    unsigned int* __restrict__ thr_raw) // (T,64), pre-zeroed
{
    __shared__ float sx[CIN][6][66];

    const int tid  = threadIdx.x;
    const int lane = tid & 63;   // w
    const int grp  = tid >> 6;   // channel group
    const int h0   = blockIdx.x * 4;
    const int b    = blockIdx.y;
    const int t    = blockIdx.z;

    const float* xb = x + ((size_t)t * BB + b) * (CIN * HW);
    for (int l = tid; l < CIN * 6 * 66; l += 256) {
        int ci  = l / 396;
        int r   = (l % 396) / 66;
        int col = l % 66;
        int gh = h0 + r - 1;
        int gw = col - 1;
        float v = 0.f;
        if (gh >= 0 && gh < HH && gw >= 0 && gw < WW)
            v = xb[ci * HW + gh * WW + gw];
        sx[ci][r][col] = v;
    }
    __syncthreads();

    float mx[CPG];
    #pragma unroll
    for (int j = 0; j < CPG; j++) mx[j] = -INFINITY;

    #pragma unroll
    for (int hr = 0; hr < 4; hr++) {
        float xv[27];
        #pragma unroll
        for (int ci = 0; ci < CIN; ci++)
            #pragma unroll
            for (int kh = 0; kh < 3; kh++)
                #pragma unroll
                for (int kw = 0; kw < 3; kw++)
                    xv[ci * 9 + kh * 3 + kw] = sx[ci][hr + kh][lane + kw];

        #pragma unroll
        for (int j = 0; j < CPG; j++) {
            const int c = grp * CPG + j;
            float acc = 0.f;
            #pragma unroll
            for (int k = 0; k < 27; k++)
                acc = fmaf(Wt[c * 27 + k], xv[k], acc);  // uniform -> s_load
            mx[j] = fmaxf(mx[j], acc);
        }
    }

    #pragma unroll
    for (int j = 0; j < CPG; j++) {
        float m = mx[j];
        #pragma unroll
        for (int off = 32; off > 0; off >>= 1)
            m = fmaxf(m, __shfl_xor(m, off, 64));
        if (lane == 0) {
            unsigned int u = __float_as_uint(m);
            u = (u & 0x80000000u) ? ~u : (u | 0x80000000u);  // sortable encode
            atomicMax(&thr_raw[t * COUT + grp * CPG + j], u);
        }
    }
}

// ---------------------------------------------------------------------------
// Pass 2: sequential T-loop. Block = one (b, h) row; 256 thr = 64 pixels x
// 4 channel-groups; mem[16] per thread in registers across all timesteps.
// WTA: per-thread argmax over its 16 channels (ascending, strict >), then a
// 4-entry LDS combine in group order — reproduces global first-argmax.
// ---------------------------------------------------------------------------
__global__ __launch_bounds__(256) void lif_kernel(
    const float* __restrict__ x,              // (T,B,3,64,64)
    const float* __restrict__ Wt,             // (64,3,3,3)
    const unsigned int* __restrict__ thr_raw, // (T,64)
    float* __restrict__ out)                  // (T,B,64,64,64)
{
    __shared__ float sx[CIN][3][66];
    __shared__ float sthr[COUT], sinv[COUT], s04[COUT], sinh_[COUT];
    __shared__ float sscore[4][64];
    __shared__ int   spack[4][64];

    const int tid  = threadIdx.x;
    const int lane = tid & 63;   // w
    const int grp  = tid >> 6;   // channel group
    const int b    = blockIdx.x >> 6;
    const int h    = blockIdx.x & 63;

    float mem[CPG];
    #pragma unroll
    for (int j = 0; j < CPG; j++) mem[j] = 0.f;

    #pragma unroll 1
    for (int t = 0; t < TT; t++) {
        __syncthreads();   // previous step's LDS reads complete

        const float* xb = x + ((size_t)t * BB + b) * (CIN * HW);
        for (int l = tid; l < CIN * 3 * 66; l += 256) {
            int ci  = l / 198;
            int r   = (l % 198) / 66;
            int col = l % 66;
            int gh = h + r - 1;
            int gw = col - 1;
            float v = 0.f;
            if (gh >= 0 && gh < HH && gw >= 0 && gw < WW)
                v = xb[ci * HW + gh * WW + gw];
            sx[ci][r][col] = v;
        }
        if (tid < COUT) {
            unsigned int u = thr_raw[t * COUT + tid];
            u = (u & 0x80000000u) ? (u & 0x7FFFFFFFu) : ~u;  // decode
            float thr = __uint_as_float(u) + 1e-4f;
            sthr[tid]  = thr;
            sinv[tid]  = 8.0f / thr;
            s04[tid]   = 0.4f * thr;
            sinh_[tid] = INH * thr;
        }
        __syncthreads();

        float xv[27];
        #pragma unroll
        for (int ci = 0; ci < CIN; ci++)
            #pragma unroll
            for (int kh = 0; kh < 3; kh++)
                #pragma unroll
                for (int kw = 0; kw < 3; kw++)
                    xv[ci * 9 + kh * 3 + kw] = sx[ci][kh][lane + kw];

        // conv (c-outer/k-inner) + ASF + LIF + local WTA over 16 channels
        float best = -INFINITY;
        int bch = 0, bsp = 0;
        #pragma unroll
        for (int j = 0; j < CPG; j++) {
            const int c = grp * CPG + j;
            float acc = 0.f;
            #pragma unroll
            for (int k = 0; k < 27; k++)
                acc = fmaf(Wt[c * 27 + k], xv[k], acc);  // uniform -> s_load
            float cur = fmaxf(acc, 0.f);
            float z   = (cur - s04[c]) * sinv[c];
            float sig = 1.0f / (1.0f + expf(-z));
            float m   = mem[j] * DECAY + sthr[c] * sig;
            mem[j] = m;
            int   s     = m > sthr[c];
            float score = s ? m : 0.f;
            if (score > best) { best = score; bch = c; bsp = s; }
        }
        sscore[grp][lane] = best;
        spack[grp][lane]  = (bch << 1) | bsp;
        __syncthreads();

        // combine the 4 group winners in ascending group order (first-argmax)
        float wbest = sscore[0][lane];
        int   wp    = spack[0][lane];
        #pragma unroll
        for (int g = 1; g < 4; g++) {
            float sc = sscore[g][lane];
            int   pk = spack[g][lane];
            if (sc > wbest) { wbest = sc; wp = pk; }
        }
        const int wwc = wp >> 1;
        const int wsp = wp & 1;

        float* ob = out + (((size_t)t * BB + b) * COUT) * HW + h * WW + lane;
        #pragma unroll
        for (int j = 0; j < CPG; j++) {
            const int c = grp * CPG + j;
            int fired = (c == wwc) && wsp;
            ob[(size_t)c * HW] = fired ? 1.f : 0.f;
            mem[j] = fired ? 0.f : (mem[j] - (wsp ? sinh_[c] : 0.f));
        }
    }
}

// ---------------------------------------------------------------------------
extern "C" void kernel_launch(void* const* d_in, const int* in_sizes, int n_in,
                              void* d_out, int out_size, void* d_ws, size_t ws_size,
                              hipStream_t stream) {
    const float* x = (const float*)d_in[0];   // (T,B,3,64,64)
    const float* W = (const float*)d_in[1];   // (64,3,3,3)
    float* out     = (float*)d_out;           // (T,B,64,64,64)

    unsigned int* thr = (unsigned int*)d_ws;  // (T,64)
    hipMemsetAsync(thr, 0, TT * COUT * sizeof(unsigned int), stream);

    thr_kernel<<<dim3(HH / 4, BB, TT), 256, 0, stream>>>(x, W, thr);
    lif_kernel<<<dim3(BB * HH), 256, 0, stream>>>(x, W, thr, out);
}

// Round 6
// 852.020 us; speedup vs baseline: 1.8167x; 1.8167x over previous
//
#include <hip/hip_runtime.h>
#include <math.h>

#define TT 10
#define BB 32
#define CIN 3
#define COUT 64
#define HH 64
#define WW 64
#define HW (HH*WW)           // 4096
#define DECAY 0.2f
#define INH 1.625f
#define CPG 16               // channels per group (one wave owns 16 channels)

// ---------------------------------------------------------------------------
// Pass 1: thr[t][c] = max over (B,H,W) of conv output.
// Block = (t, b, 4-row group); 256 thr = 64 pixels x 4 channel-groups.
// Weight base made provably wave-uniform via readfirstlane -> s_load batches.
// ---------------------------------------------------------------------------
__global__ __launch_bounds__(256, 4) void thr_kernel(
    const float* __restrict__ x,        // (T,B,3,64,64)
    const float* __restrict__ Wt,       // (64,3,3,3)
    unsigned int* __restrict__ thr_raw) // (T,64), pre-zeroed
{
    __shared__ float sx[CIN][6][66];

    const int tid  = threadIdx.x;
    const int lane = tid & 63;   // w
    const int grp  = tid >> 6;   // channel group (wave-uniform)
    const int h0   = blockIdx.x * 4;
    const int b    = blockIdx.y;
    const int t    = blockIdx.z;

    // provably wave-uniform weight base -> scalar loads
    const float* wg = Wt + __builtin_amdgcn_readfirstlane(grp * CPG * 27);

    const float* xb = x + ((size_t)t * BB + b) * (CIN * HW);
    for (int l = tid; l < CIN * 6 * 66; l += 256) {
        int ci  = l / 396;
        int r   = (l % 396) / 66;
        int col = l % 66;
        int gh = h0 + r - 1;
        int gw = col - 1;
        float v = 0.f;
        if (gh >= 0 && gh < HH && gw >= 0 && gw < WW)
            v = xb[ci * HW + gh * WW + gw];
        sx[ci][r][col] = v;
    }
    __syncthreads();

    float mx[CPG];
    #pragma unroll
    for (int j = 0; j < CPG; j++) mx[j] = -INFINITY;

    #pragma unroll
    for (int hr = 0; hr < 4; hr++) {
        float xv[27];
        #pragma unroll
        for (int ci = 0; ci < CIN; ci++)
            #pragma unroll
            for (int kh = 0; kh < 3; kh++)
                #pragma unroll
                for (int kw = 0; kw < 3; kw++)
                    xv[ci * 9 + kh * 3 + kw] = sx[ci][hr + kh][lane + kw];

        #pragma unroll
        for (int j = 0; j < CPG; j++) {
            float acc = 0.f;
            #pragma unroll
            for (int k = 0; k < 27; k++)
                acc = fmaf(wg[j * 27 + k], xv[k], acc);  // s_load (uniform)
            mx[j] = fmaxf(mx[j], acc);
        }
    }

    #pragma unroll
    for (int j = 0; j < CPG; j++) {
        float m = mx[j];
        #pragma unroll
        for (int off = 32; off > 0; off >>= 1)
            m = fmaxf(m, __shfl_xor(m, off, 64));
        if (lane == 0) {
            unsigned int u = __float_as_uint(m);
            u = (u & 0x80000000u) ? ~u : (u | 0x80000000u);  // sortable encode
            atomicMax(&thr_raw[t * COUT + grp * CPG + j], u);
        }
    }
}

// ---------------------------------------------------------------------------
// Pass 2: sequential T-loop. Block = one (b, h) row; 256 thr = 64 pixels x
// 4 channel-groups; mem[16] per thread in registers across all timesteps.
// WTA: per-thread argmax over its 16 channels (ascending, strict >), then a
// 4-entry LDS combine in group order — reproduces global first-argmax.
// ---------------------------------------------------------------------------
__global__ __launch_bounds__(256, 4) void lif_kernel(
    const float* __restrict__ x,              // (T,B,3,64,64)
    const float* __restrict__ Wt,             // (64,3,3,3)
    const unsigned int* __restrict__ thr_raw, // (T,64)
    float* __restrict__ out)                  // (T,B,64,64,64)
{
    __shared__ float sx[CIN][3][66];
    __shared__ float sthr[COUT], sinv[COUT], s04[COUT], sinh_[COUT];
    __shared__ float sscore[4][64];
    __shared__ int   spack[4][64];

    const int tid  = threadIdx.x;
    const int lane = tid & 63;   // w
    const int grp  = tid >> 6;   // channel group (wave-uniform)
    const int b    = blockIdx.x >> 6;
    const int h    = blockIdx.x & 63;

    // provably wave-uniform weight base -> scalar loads
    const float* wg = Wt + __builtin_amdgcn_readfirstlane(grp * CPG * 27);

    float mem[CPG];
    #pragma unroll
    for (int j = 0; j < CPG; j++) mem[j] = 0.f;

    #pragma unroll 1
    for (int t = 0; t < TT; t++) {
        __syncthreads();   // previous step's LDS reads complete

        const float* xb = x + ((size_t)t * BB + b) * (CIN * HW);
        for (int l = tid; l < CIN * 3 * 66; l += 256) {
            int ci  = l / 198;
            int r   = (l % 198) / 66;
            int col = l % 66;
            int gh = h + r - 1;
            int gw = col - 1;
            float v = 0.f;
            if (gh >= 0 && gh < HH && gw >= 0 && gw < WW)
                v = xb[ci * HW + gh * WW + gw];
            sx[ci][r][col] = v;
        }
        if (tid < COUT) {
            unsigned int u = thr_raw[t * COUT + tid];
            u = (u & 0x80000000u) ? (u & 0x7FFFFFFFu) : ~u;  // decode
            float thr = __uint_as_float(u) + 1e-4f;
            sthr[tid]  = thr;
            sinv[tid]  = 8.0f / thr;
            s04[tid]   = 0.4f * thr;
            sinh_[tid] = INH * thr;
        }
        __syncthreads();

        float xv[27];
        #pragma unroll
        for (int ci = 0; ci < CIN; ci++)
            #pragma unroll
            for (int kh = 0; kh < 3; kh++)
                #pragma unroll
                for (int kw = 0; kw < 3; kw++)
                    xv[ci * 9 + kh * 3 + kw] = sx[ci][kh][lane + kw];

        // conv (c-outer/k-inner) + ASF + LIF + local WTA over 16 channels
        float best = -INFINITY;
        int bch = 0, bsp = 0;
        #pragma unroll
        for (int j = 0; j < CPG; j++) {
            const int c = grp * CPG + j;
            float acc = 0.f;
            #pragma unroll
            for (int k = 0; k < 27; k++)
                acc = fmaf(wg[j * 27 + k], xv[k], acc);  // s_load (uniform)
            float cur = fmaxf(acc, 0.f);
            float z   = (cur - s04[c]) * sinv[c];
            float sig = 1.0f / (1.0f + expf(-z));
            float m   = mem[j] * DECAY + sthr[c] * sig;
            mem[j] = m;
            int   s     = m > sthr[c];
            float score = s ? m : 0.f;
            if (score > best) { best = score; bch = c; bsp = s; }
        }
        sscore[grp][lane] = best;
        spack[grp][lane]  = (bch << 1) | bsp;
        __syncthreads();

        // combine the 4 group winners in ascending group order (first-argmax)
        float wbest = sscore[0][lane];
        int   wp    = spack[0][lane];
        #pragma unroll
        for (int g = 1; g < 4; g++) {
            float sc = sscore[g][lane];
            int   pk = spack[g][lane];
            if (sc > wbest) { wbest = sc; wp = pk; }
        }
        const int wwc = wp >> 1;
        const int wsp = wp & 1;

        float* ob = out + (((size_t)t * BB + b) * COUT) * HW + h * WW + lane;
        #pragma unroll
        for (int j = 0; j < CPG; j++) {
            const int c = grp * CPG + j;
            int fired = (c == wwc) && wsp;
            ob[(size_t)c * HW] = fired ? 1.f : 0.f;
            mem[j] = fired ? 0.f : (mem[j] - (wsp ? sinh_[c] : 0.f));
        }
    }
}

// ---------------------------------------------------------------------------
extern "C" void kernel_launch(void* const* d_in, const int* in_sizes, int n_in,
                              void* d_out, int out_size, void* d_ws, size_t ws_size,
                              hipStream_t stream) {
    const float* x = (const float*)d_in[0];   // (T,B,3,64,64)
    const float* W = (const float*)d_in[1];   // (64,3,3,3)
    float* out     = (float*)d_out;           // (T,B,64,64,64)

    unsigned int* thr = (unsigned int*)d_ws;  // (T,64)
    hipMemsetAsync(thr, 0, TT * COUT * sizeof(unsigned int), stream);

    thr_kernel<<<dim3(HH / 4, BB, TT), 256, 0, stream>>>(x, W, thr);
    lif_kernel<<<dim3(BB * HH), 256, 0, stream>>>(x, W, thr, out);
}

// Round 7
// 709.384 us; speedup vs baseline: 2.1820x; 1.2011x over previous
//
#include <hip/hip_runtime.h>
#include <math.h>

#define TT 10
#define BB 32
#define CIN 3
#define COUT 64
#define HH 64
#define WW 64
#define HW (HH*WW)           // 4096
#define DECAY 0.2f
#define INH 1.625f

__device__ __forceinline__ unsigned int enc_f(float f) {
    unsigned int u = __float_as_uint(f);
    return (u & 0x80000000u) ? ~u : (u | 0x80000000u);
}
__device__ __forceinline__ float dec_f(unsigned int u) {
    u = (u & 0x80000000u) ? (u & 0x7FFFFFFFu) : ~u;
    return __uint_as_float(u);
}

// ---------------------------------------------------------------------------
// Pass 1: thr[t][c] = max over (B,H,W) of conv. lane = channel.
// W[27] per-lane in VGPRs (loaded once). x window values are wave-uniform ->
// s_load into SGPRs; v_fma takes the SGPR operand. Each wave sweeps one row.
// Grid (16 rowgroups, 32 b, 10 t) x 256 (4 waves x 1 row each).
// ---------------------------------------------------------------------------
__global__ __launch_bounds__(256) void thr_kernel(
    const float* __restrict__ x,        // (T,B,3,64,64)
    const float* __restrict__ Wt,       // (64,3,3,3)
    unsigned int* __restrict__ thr_raw) // (T,64), pre-zeroed
{
    __shared__ float wmax[4][COUT];

    const int tid  = threadIdx.x;
    const int lane = tid & 63;                 // channel
    const int wave = tid >> 6;
    const int hu   = __builtin_amdgcn_readfirstlane(blockIdx.x * 4 + (tid >> 6));
    const int b    = blockIdx.y;
    const int t    = blockIdx.z;

    // per-lane weights for channel = lane (resident all kernel)
    float w[27];
    #pragma unroll
    for (int k = 0; k < 27; k++) w[k] = Wt[lane * 27 + k];

    const float* xb = x + ((size_t)t * BB + b) * (CIN * HW);

    float mx = -INFINITY;

    #pragma unroll
    for (int cc = 0; cc < 16; cc++) {          // 16 chunks of 4 pixels
        // wave-uniform x window: 3 cin x 3 rows x 6 cols -> SGPRs
        float sxv[CIN][3][6];
        #pragma unroll
        for (int ci = 0; ci < CIN; ci++)
            #pragma unroll
            for (int kh = 0; kh < 3; kh++) {
                int r  = hu + kh - 1;
                int rv = (r >= 0) && (r < HH);
                int rc = rv ? r : 0;
                #pragma unroll
                for (int u = 0; u < 6; u++) {
                    int col = cc * 4 - 1 + u;          // compile-time
                    int cv  = (col >= 0) && (col < WW);
                    int c2  = cv ? col : 0;
                    float v = xb[ci * HW + rc * WW + c2];   // uniform -> s_load
                    sxv[ci][kh][u] = (rv && cv) ? v : 0.f;
                }
            }
        #pragma unroll
        for (int j = 0; j < 4; j++) {
            float acc = 0.f;
            #pragma unroll
            for (int ci = 0; ci < CIN; ci++)
                #pragma unroll
                for (int kh = 0; kh < 3; kh++)
                    #pragma unroll
                    for (int kw = 0; kw < 3; kw++)
                        acc = fmaf(w[ci * 9 + kh * 3 + kw],
                                   sxv[ci][kh][j + kw], acc);
            mx = fmaxf(mx, acc);
        }
    }

    wmax[wave][lane] = mx;
    __syncthreads();
    if (wave == 0) {
        float m = fmaxf(fmaxf(wmax[0][lane], wmax[1][lane]),
                        fmaxf(wmax[2][lane], wmax[3][lane]));
        atomicMax(&thr_raw[t * COUT + lane], enc_f(m));
    }
}

// ---------------------------------------------------------------------------
// Pass 2: sequential T-loop. lane = channel; wave owns 16 pixels of one
// (b,h) row; mem[16] per thread. Conv operands: W in VGPR, x window in SGPR.
// WTA = within-wave butterfly, predicated on ballot (spikes are rare).
// Output: coalesced zero-fill + sparse winner stores (barrier between).
// Grid = B*H = 2048 blocks x 256.
// ---------------------------------------------------------------------------
__global__ __launch_bounds__(256) void lif_kernel(
    const float* __restrict__ x,              // (T,B,3,64,64)
    const float* __restrict__ Wt,             // (64,3,3,3)
    const unsigned int* __restrict__ thr_raw, // (T,64)
    float* __restrict__ out)                  // (T,B,64,64,64)
{
    const int tid  = threadIdx.x;
    const int lane = tid & 63;                              // channel
    const int p0   = __builtin_amdgcn_readfirstlane((tid >> 6) * 16);
    const int b    = blockIdx.x >> 6;
    const int h    = blockIdx.x & 63;

    float w[27];
    #pragma unroll
    for (int k = 0; k < 27; k++) w[k] = Wt[lane * 27 + k];

    float mem[16];
    #pragma unroll
    for (int j = 0; j < 16; j++) mem[j] = 0.f;

    #pragma unroll 1
    for (int t = 0; t < TT; t++) {
        float* os = out + (((size_t)t * BB + b) * COUT) * HW + h * WW;

        // coalesced zero-fill of this block's (t,b,:,h,:) slab
        #pragma unroll
        for (int g = 0; g < 4; g++) {
            int c  = g * 16 + (tid >> 4);
            int w4 = (tid & 15) * 4;
            *(float4*)(os + (size_t)c * HW + w4) = make_float4(0.f, 0.f, 0.f, 0.f);
        }

        // per-lane (= per-channel) threshold constants
        float thr  = dec_f(thr_raw[t * COUT + lane]) + 1e-4f;
        float sinv = 8.0f / thr;
        float s04  = 0.4f * thr;
        float sinh_ = INH * thr;

        const float* xb = x + ((size_t)t * BB + b) * (CIN * HW);

        int fmask = 0;   // bit j: this lane's channel fired at pixel p0+j

        #pragma unroll
        for (int cc = 0; cc < 4; cc++) {       // 4 chunks of 4 pixels
            float sxv[CIN][3][6];              // wave-uniform -> SGPRs
            #pragma unroll
            for (int ci = 0; ci < CIN; ci++)
                #pragma unroll
                for (int kh = 0; kh < 3; kh++) {
                    int r  = h + kh - 1;
                    int rv = (r >= 0) && (r < HH);
                    int rc = rv ? r : 0;
                    #pragma unroll
                    for (int u = 0; u < 6; u++) {
                        int col = p0 + cc * 4 - 1 + u;     // wave-uniform
                        int cv  = (col >= 0) && (col < WW);
                        int c2  = cv ? col : 0;
                        float v = xb[ci * HW + rc * WW + c2]; // s_load
                        sxv[ci][kh][u] = (rv && cv) ? v : 0.f;
                    }
                }
            #pragma unroll
            for (int j4 = 0; j4 < 4; j4++) {
                const int j = cc * 4 + j4;
                float acc = 0.f;
                #pragma unroll
                for (int ci = 0; ci < CIN; ci++)
                    #pragma unroll
                    for (int kh = 0; kh < 3; kh++)
                        #pragma unroll
                        for (int kw = 0; kw < 3; kw++)
                            acc = fmaf(w[ci * 9 + kh * 3 + kw],
                                       sxv[ci][kh][j4 + kw], acc);
                // ASF + LIF (identical math/order to round 6)
                float cur = fmaxf(acc, 0.f);
                float z   = (cur - s04) * sinv;
                float sig = 1.0f / (1.0f + expf(-z));
                float m   = mem[j] * DECAY + thr * sig;
                int   sp  = m > thr;
                float score = sp ? m : 0.f;

                unsigned long long blt = __ballot(sp);
                int fr = 0, sp_any = 0;
                if (blt) {   // wave-uniform; rare (ATB thresholds ~ batch max)
                    // within-wave first-argmax of score (tie -> lower channel)
                    float bs = score;
                    int   bc = lane;
                    #pragma unroll
                    for (int off = 32; off > 0; off >>= 1) {
                        float so = __shfl_xor(bs, off, 64);
                        int   co = __shfl_xor(bc, off, 64);
                        if (so > bs || (so == bs && co < bc)) { bs = so; bc = co; }
                    }
                    int spw = __shfl(sp, bc, 64);   // did the winner spike?
                    fr     = (lane == bc) && sp;
                    sp_any = spw;
                }
                mem[j] = fr ? 0.f : (m - (sp_any ? sinh_ : 0.f));
                if (fr) fmask |= (1 << j);
            }
        }

        __syncthreads();   // drain zero-fill stores before winner stores

        if (fmask) {
            #pragma unroll
            for (int j = 0; j < 16; j++)
                if (fmask & (1 << j))
                    os[(size_t)lane * HW + p0 + j] = 1.0f;
        }
    }
}

// ---------------------------------------------------------------------------
extern "C" void kernel_launch(void* const* d_in, const int* in_sizes, int n_in,
                              void* d_out, int out_size, void* d_ws, size_t ws_size,
                              hipStream_t stream) {
    const float* x = (const float*)d_in[0];   // (T,B,3,64,64)
    const float* W = (const float*)d_in[1];   // (64,3,3,3)
    float* out     = (float*)d_out;           // (T,B,64,64,64)

    unsigned int* thr = (unsigned int*)d_ws;  // (T,64)
    hipMemsetAsync(thr, 0, TT * COUT * sizeof(unsigned int), stream);

    thr_kernel<<<dim3(HH / 4, BB, TT), 256, 0, stream>>>(x, W, thr);
    lif_kernel<<<dim3(BB * HH), 256, 0, stream>>>(x, W, thr, out);
}

// Round 8
// 544.570 us; speedup vs baseline: 2.8424x; 1.3026x over previous
//
#include <hip/hip_runtime.h>
#include <math.h>

#define TT 10
#define BB 32
#define CIN 3
#define COUT 64
#define HH 64
#define WW 64
#define HW (HH*WW)           // 4096
#define DECAY 0.2f
#define INH 1.625f

#define ISLAB ((size_t)HW * COUT)          // elems per (t,b) i-slab: 262144

__device__ __forceinline__ unsigned int enc_f(float f) {
    unsigned int u = __float_as_uint(f);
    return (u & 0x80000000u) ? ~u : (u | 0x80000000u);
}
__device__ __forceinline__ float dec_f(unsigned int u) {
    u = (u & 0x80000000u) ? (u & 0x7FFFFFFFu) : ~u;
    return __uint_as_float(u);
}

// ---------------------------------------------------------------------------
// Pass 1: conv ONCE + threshold max, t-parallel.
// lane = channel (W[27] per-lane VGPRs, loaded once). x window comes from an
// LDS tile via wave-uniform vector reads (broadcast, conflict-free) — zero
// scalar-memory traffic in the loop. i stored [t][b][h][w][c] (lane=c ->
// coalesced 256B/pixel). Grid (16 rowgroups, B, nt) x 256 (wave = row).
// ---------------------------------------------------------------------------
__global__ __launch_bounds__(256) void conv_kernel(
    const float* __restrict__ x,        // (T,B,3,64,64)
    const float* __restrict__ Wt,       // (64,3,3,3)
    float* __restrict__ ibuf,           // slot-major [nt][B][H][W][C]
    unsigned int* __restrict__ thr_raw, // (T,64) pre-zeroed
    int t0)
{
    __shared__ float sx[CIN][6][68];    // row stride 68 -> 16B-aligned rows
    __shared__ float wmax[4][COUT];

    const int tid  = threadIdx.x;
    const int lane = tid & 63;          // channel
    const int wave = tid >> 6;          // row within 4-row group
    const int h0   = blockIdx.x * 4;
    const int b    = blockIdx.y;
    const int t    = t0 + blockIdx.z;

    // per-lane weights, channel = lane, resident whole kernel
    float w[27];
    #pragma unroll
    for (int k = 0; k < 27; k++) w[k] = Wt[lane * 27 + k];

    // stage x tile (3 x 6 x 66 used cols), coalesced, zero-padded
    const float* xb = x + ((size_t)t * BB + b) * (CIN * HW);
    for (int l = tid; l < CIN * 6 * 66; l += 256) {
        int ci  = l / 396;
        int r   = (l % 396) / 66;
        int col = l % 66;
        int gh = h0 + r - 1;
        int gw = col - 1;
        float v = 0.f;
        if (gh >= 0 && gh < HH && gw >= 0 && gw < WW)
            v = xb[ci * HW + gh * WW + gw];
        sx[ci][r][col] = v;
    }
    __syncthreads();

    const int h = h0 + wave;
    float* ist = ibuf + ((size_t)blockIdx.z * BB + b) * ISLAB
                      + (size_t)h * WW * COUT;

    float mx = -INFINITY;

    for (int cc = 0; cc < 16; cc++) {          // 4-pixel chunks along the row
        float acc0 = 0.f, acc1 = 0.f, acc2 = 0.f, acc3 = 0.f;
        #pragma unroll
        for (int ci = 0; ci < CIN; ci++)
            #pragma unroll
            for (int kh = 0; kh < 3; kh++) {
                // wave-uniform LDS reads: 6 floats = b128 + b64 (broadcast)
                const float* rp = &sx[ci][wave + kh][cc * 4];
                float4 q = *(const float4*)rp;
                float2 r2 = *(const float2*)(rp + 4);
                float x0 = q.x, x1 = q.y, x2 = q.z, x3 = q.w;
                float x4 = r2.x, x5 = r2.y;
                const float w0 = w[ci * 9 + kh * 3 + 0];
                const float w1 = w[ci * 9 + kh * 3 + 1];
                const float w2 = w[ci * 9 + kh * 3 + 2];
                // kw ascending per pixel -> same accumulation order as before
                acc0 = fmaf(w0, x0, acc0); acc0 = fmaf(w1, x1, acc0); acc0 = fmaf(w2, x2, acc0);
                acc1 = fmaf(w0, x1, acc1); acc1 = fmaf(w1, x2, acc1); acc1 = fmaf(w2, x3, acc1);
                acc2 = fmaf(w0, x2, acc2); acc2 = fmaf(w1, x3, acc2); acc2 = fmaf(w2, x4, acc2);
                acc3 = fmaf(w0, x3, acc3); acc3 = fmaf(w1, x4, acc3); acc3 = fmaf(w2, x5, acc3);
            }
        mx = fmaxf(mx, fmaxf(fmaxf(acc0, acc1), fmaxf(acc2, acc3)));
        // coalesced stores: 256B per pixel (lane = c)
        ist[(size_t)(cc * 4 + 0) * COUT + lane] = acc0;
        ist[(size_t)(cc * 4 + 1) * COUT + lane] = acc1;
        ist[(size_t)(cc * 4 + 2) * COUT + lane] = acc2;
        ist[(size_t)(cc * 4 + 3) * COUT + lane] = acc3;
    }

    wmax[wave][lane] = mx;
    __syncthreads();
    if (wave == 0) {
        float m = fmaxf(fmaxf(wmax[0][lane], wmax[1][lane]),
                        fmaxf(wmax[2][lane], wmax[3][lane]));
        atomicMax(&thr_raw[t * COUT + lane], enc_f(m));
    }
}

// ---------------------------------------------------------------------------
// Pass 2: pure LIF stream (no conv, no weights, no scalar loads).
// lane = channel; wave owns 16 pixels of one (b,h) row; mem[16] in registers.
// i read coalesced from [.][h][w][c]; WTA = ballot-gated wave butterfly;
// output = zero-fill + sparse winner stores (r7-proven).
// Grid = B*H = 2048 blocks x 256.
// ---------------------------------------------------------------------------
__global__ __launch_bounds__(256) void lif_kernel(
    const float* __restrict__ ibuf,           // [nt][B][H][W][C]
    const unsigned int* __restrict__ thr_raw, // (T,64)
    float* __restrict__ out,                  // (T,B,64,64,64)
    float* __restrict__ memws,                // [B][H][W][C] (slow path)
    int t0, int nt)
{
    const int tid  = threadIdx.x;
    const int lane = tid & 63;                              // channel
    const int p0   = __builtin_amdgcn_readfirstlane((tid >> 6) * 16);
    const int b    = blockIdx.x >> 6;
    const int h    = blockIdx.x & 63;

    float* mrow = memws + ((size_t)b * HH + h) * WW * COUT;

    float mem[16];
    if (t0 == 0) {
        #pragma unroll
        for (int j = 0; j < 16; j++) mem[j] = 0.f;
    } else {
        #pragma unroll
        for (int j = 0; j < 16; j++)
            mem[j] = mrow[(size_t)(p0 + j) * COUT + lane];  // coalesced
    }

    #pragma unroll 1
    for (int tt = 0; tt < nt; tt++) {
        const int t = t0 + tt;
        const float* ild = ibuf + ((size_t)tt * BB + b) * ISLAB
                                + (size_t)h * WW * COUT;
        float* os = out + (((size_t)t * BB + b) * COUT) * HW + h * WW;

        // coalesced zero-fill of this block's (t,b,:,h,:) slab
        #pragma unroll
        for (int g = 0; g < 4; g++) {
            int c  = g * 16 + (tid >> 4);
            int w4 = (tid & 15) * 4;
            *(float4*)(os + (size_t)c * HW + w4) = make_float4(0.f, 0.f, 0.f, 0.f);
        }

        // per-lane (= per-channel) threshold constants
        float thr   = dec_f(thr_raw[t * COUT + lane]) + 1e-4f;
        float sinv  = 8.0f / thr;
        float s04   = 0.4f * thr;
        float sinh_ = INH * thr;

        int fmask = 0;   // bit j: this lane's channel fired at pixel p0+j

        #pragma unroll
        for (int j = 0; j < 16; j++) {
            float iv  = ild[(size_t)(p0 + j) * COUT + lane];  // coalesced
            float cur = fmaxf(iv, 0.f);
            float z   = (cur - s04) * sinv;
            float sig = 1.0f / (1.0f + expf(-z));
            float m   = mem[j] * DECAY + thr * sig;
            int   sp  = m > thr;
            float score = sp ? m : 0.f;

            unsigned long long blt = __ballot(sp);
            int fr = 0, sp_any = 0;
            if (blt) {   // wave-uniform; rare
                float bs = score;
                int   bc = lane;
                #pragma unroll
                for (int off = 32; off > 0; off >>= 1) {
                    float so = __shfl_xor(bs, off, 64);
                    int   co = __shfl_xor(bc, off, 64);
                    if (so > bs || (so == bs && co < bc)) { bs = so; bc = co; }
                }
                int spw = __shfl(sp, bc, 64);   // winner's spike = any_sp
                fr     = (lane == bc) && sp;
                sp_any = spw;
            }
            mem[j] = fr ? 0.f : (m - (sp_any ? sinh_ : 0.f));
            if (fr) fmask |= (1 << j);
        }

        __syncthreads();   // drain zero-fill before winner stores

        if (fmask) {
            #pragma unroll
            for (int j = 0; j < 16; j++)
                if (fmask & (1 << j))
                    os[(size_t)lane * HW + p0 + j] = 1.0f;
        }
        __syncthreads();
    }

    if (t0 + nt < TT) {   // slow path: persist membrane
        #pragma unroll
        for (int j = 0; j < 16; j++)
            mrow[(size_t)(p0 + j) * COUT + lane] = mem[j];
    }
}

// ---------------------------------------------------------------------------
extern "C" void kernel_launch(void* const* d_in, const int* in_sizes, int n_in,
                              void* d_out, int out_size, void* d_ws, size_t ws_size,
                              hipStream_t stream) {
    const float* x = (const float*)d_in[0];   // (T,B,3,64,64)
    const float* W = (const float*)d_in[1];   // (64,3,3,3)
    float* out     = (float*)d_out;           // (T,B,64,64,64)

    char* ws = (char*)d_ws;
    unsigned int* thr = (unsigned int*)ws;                    // (T,64)
    const size_t IOFF   = 65536;
    const size_t SLABB  = ISLAB * sizeof(float);              // 33.55 MB

    hipMemsetAsync(thr, 0, TT * COUT * sizeof(unsigned int), stream);

    if (ws_size >= IOFF + TT * SLABB) {
        // fast path: all t at once, i fully materialized, mem stays in regs
        float* ibuf = (float*)(ws + IOFF);
        conv_kernel<<<dim3(HH / 4, BB, TT), 256, 0, stream>>>(x, W, ibuf, thr, 0);
        lif_kernel<<<dim3(BB * HH), 256, 0, stream>>>(ibuf, thr, out,
                                                      (float*)(ws + IOFF), 0, TT);
    } else {
        // slow path: per-t ping-pong; membrane persists in ws
        float* ibuf  = (float*)(ws + IOFF);
        float* memws = (float*)(ws + IOFF + SLABB);
        for (int t = 0; t < TT; t++) {
            conv_kernel<<<dim3(HH / 4, BB, 1), 256, 0, stream>>>(x, W, ibuf, thr, t);
            lif_kernel<<<dim3(BB * HH), 256, 0, stream>>>(ibuf, thr, out,
                                                          memws, t, 1);
        }
    }
}